// Round 13
// baseline (133.849 us; speedup 1.0000x reference)
//
#include <hip/hip_runtime.h>
#include <math.h>

// Problem constants (B=2, S=1024, H=12, HS=64, ALL=768, P=128)
#define SEQ   1024
#define BATCH 2
#define NH    12
#define ALLD  768
// 1/scaling = 1/64^0.25
#define INVS  0.35355339059327373f

typedef __attribute__((ext_vector_type(8)))  __bf16 bf16x8;
typedef __attribute__((ext_vector_type(16))) float  f32x16;
typedef __attribute__((ext_vector_type(2)))  float  f32x2;

// ---------------------------------------------------------------------------
// K1: u = p1 @ W_qk + b_qk, scaled by INVS; emit q/k in MFMA frag layout.
//   qf/kf [b][h][ks4][half][row][8]   (bf16)
// (unchanged from R7/R10/R12 anchor)
// ---------------------------------------------------------------------------
__global__ __launch_bounds__(256) void qk_gemm(
    const float* __restrict__ p1, const float* __restrict__ Wqk,
    const float* __restrict__ bqk, __bf16* __restrict__ qf,
    __bf16* __restrict__ kf) {
  const int tid = threadIdx.x;
  const int l = tid & 63, w = tid >> 6;
  const int l31 = l & 31, half = l >> 5;
  const int m0 = blockIdx.x * 64;
  const int mw = (w >> 1) * 32;
  const int nw = blockIdx.y * 64 + (w & 1) * 32;

  __shared__ __bf16 Af[8][66][8];  // 8448 B, padded rows -> conflict-free

  f32x16 acc;
#pragma unroll
  for (int e = 0; e < 16; ++e) acc[e] = 0.f;

  const int arow = tid >> 2;       // 0..63
  const int aq = tid & 3;          // k-quarter (16 floats)

  for (int kk = 0; kk < 768; kk += 64) {
    __syncthreads();  // WAR on Af
    {
      const float* ap = p1 + (size_t)(m0 + arow) * 768 + kk + aq * 16;
      float4 a0 = ((const float4*)ap)[0];
      float4 a1 = ((const float4*)ap)[1];
      float4 a2 = ((const float4*)ap)[2];
      float4 a3 = ((const float4*)ap)[3];
      bf16x8 f0, f1;
      f0[0] = (__bf16)a0.x; f0[1] = (__bf16)a0.y;
      f0[2] = (__bf16)a0.z; f0[3] = (__bf16)a0.w;
      f0[4] = (__bf16)a1.x; f0[5] = (__bf16)a1.y;
      f0[6] = (__bf16)a1.z; f0[7] = (__bf16)a1.w;
      f1[0] = (__bf16)a2.x; f1[1] = (__bf16)a2.y;
      f1[2] = (__bf16)a2.z; f1[3] = (__bf16)a2.w;
      f1[4] = (__bf16)a3.x; f1[5] = (__bf16)a3.y;
      f1[6] = (__bf16)a3.z; f1[7] = (__bf16)a3.w;
      *(bf16x8*)&Af[aq * 2 + 0][arow][0] = f0;
      *(bf16x8*)&Af[aq * 2 + 1][arow][0] = f1;
    }
    __syncthreads();
#pragma unroll
    for (int ksl = 0; ksl < 4; ++ksl) {
      const float* bsrc =
          Wqk + (size_t)(kk + ksl * 16 + half * 8) * 1536 + nw + l31;
      bf16x8 bf;
#pragma unroll
      for (int e = 0; e < 8; ++e) bf[e] = (__bf16)bsrc[(size_t)e * 1536];
      bf16x8 af = *(const bf16x8*)&Af[ksl * 2 + half][mw + l31][0];
      acc = __builtin_amdgcn_mfma_f32_32x32x16_bf16(af, bf, acc, 0, 0, 0);
    }
  }

  const int n = nw + l31;
  const float bias = bqk[n];
  const bool is_q = (n < ALLD);
  const int nn = is_q ? n : n - ALLD;
  const int h = nn >> 6, dd = nn & 63;
  const int ks4 = dd >> 4, hf = (dd >> 3) & 1, e = dd & 7;
  __bf16* fdst = is_q ? qf : kf;
#pragma unroll
  for (int r = 0; r < 16; ++r) {
    const int m = m0 + mw + (r & 3) + 8 * (r >> 2) + 4 * half;
    const int bb = m >> 10, ss = m & 1023;
    const float v = (acc[r] + bias) * INVS;
    fdst[((((size_t)(bb * NH + h) * 4 + ks4) * 2 + hf) * SEQ + ss) * 8 + e] =
        (__bf16)v;
  }
}

// ---------------------------------------------------------------------------
// K2: fused scores + in-tile rel bias + writer + nt-store.
// R12 structure (one 32x32 tile/block, relfrags direct from global rel).
// R13 change: packed epilogue — v_cvt_pk_bf16_f32 packs both bias
// candidates (bacc0, bacc1) into one u32, ONE __shfl moves both, half-
// select + shl16 rebuilds f32. Halves ds_bpermute count (96->48/wave).
// INVS pre-folded into relfrag build (identical math placement).
// ---------------------------------------------------------------------------
__global__ __launch_bounds__(256, 4) void main_kernel(
    const __bf16* __restrict__ qf, const __bf16* __restrict__ kf,
    const float* __restrict__ rel, const float* __restrict__ Wout,
    const float* __restrict__ bout, float* __restrict__ out) {
  const int tid = threadIdx.x;
  const int l = tid & 63, w = tid >> 6;
  const int l31 = l & 31, half = l >> 5;

  // bijective XCD swizzle (nwg = 2048, divisible by 8)
  const int raw = blockIdx.x + (blockIdx.y << 5) + (blockIdx.z << 10);
  const int swz = (raw & 7) * 256 + (raw >> 3);
  const int t0 = (swz & 31) * 32;
  const int s0 = ((swz >> 5) & 31) * 32;
  const int b = swz >> 10;
  const int D = t0 - s0;

  __shared__ __bf16 P[1024][20];  // 40 KB, padded rows -> conflict-free

  // ---- bias B-frags straight from global rel (L2-hot), INVS folded:
  //      panel col c = cb*32 + l31  <->  d = D-32+c
  bf16x8 relfrag[4][2];
#pragma unroll
  for (int cb = 0; cb < 2; ++cb) {
    const int c = cb * 32 + l31;
    const int d = D - 32 + c;
    const int id = (d >= 0) ? (d < 127 ? d : 127) : (d > -127 ? d + 256 : 129);
    const float* rrow = rel + (size_t)id * 64 + half * 8;
#pragma unroll
    for (int ks = 0; ks < 4; ++ks) {
      float4 r0 = *(const float4*)(rrow + ks * 16);
      float4 r1 = *(const float4*)(rrow + ks * 16 + 4);
      bf16x8 f;
      f[0] = (__bf16)(r0.x * INVS); f[1] = (__bf16)(r0.y * INVS);
      f[2] = (__bf16)(r0.z * INVS); f[3] = (__bf16)(r0.w * INVS);
      f[4] = (__bf16)(r1.x * INVS); f[5] = (__bf16)(r1.y * INVS);
      f[6] = (__bf16)(r1.z * INVS); f[7] = (__bf16)(r1.w * INVS);
      relfrag[ks][cb] = f;
    }
  }

  // zero the pad heads 12..15
  {
    ushort4 z = {0, 0, 0, 0};
#pragma unroll
    for (int i = 0; i < 4; ++i) *(ushort4*)&P[tid * 4 + i][12] = z;
  }

  const bf16x8* qfp = (const bf16x8*)qf;
  const bf16x8* kfp = (const bf16x8*)kf;

  // -------- QK + bias phase: 3 heads per wave --------
#pragma unroll
  for (int hh = 0; hh < 3; ++hh) {
    const int h = w * 3 + hh;
    f32x16 acc, bacc0, bacc1;
#pragma unroll
    for (int e = 0; e < 16; ++e) { acc[e] = 0.f; bacc0[e] = 0.f; bacc1[e] = 0.f; }
#pragma unroll
    for (int ks = 0; ks < 4; ++ks) {
      const size_t pbase = (((size_t)(b * NH + h) * 4 + ks) * 2 + half) * SEQ;
      bf16x8 af = qfp[pbase + s0 + l31];
      bf16x8 bvk = kfp[pbase + t0 + l31];
      acc = __builtin_amdgcn_mfma_f32_32x32x16_bf16(af, bvk, acc, 0, 0, 0);
      bacc0 = __builtin_amdgcn_mfma_f32_32x32x16_bf16(af, relfrag[ks][0],
                                                      bacc0, 0, 0, 0);
      bacc1 = __builtin_amdgcn_mfma_f32_32x32x16_bf16(af, relfrag[ks][1],
                                                      bacc1, 0, 0, 0);
    }
    // packed diagonal extract: pk = {lo: bf16(bacc0), hi: bf16(bacc1)};
    // one shfl moves both candidates; dest lane l31 takes hi if l31>=sl.
#pragma unroll
    for (int r = 0; r < 16; ++r) {
      const int sl = (r & 3) + 8 * (r >> 2) + 4 * half;
      unsigned int pk;
      asm("v_cvt_pk_bf16_f32 %0, %1, %2"
          : "=v"(pk)
          : "v"(bacc0[r]), "v"(bacc1[r]));
      const unsigned int moved =
          (unsigned int)__shfl((int)pk, (l31 - sl) & 31, 32);
      const unsigned int sel =
          (l31 >= sl) ? (moved & 0xffff0000u) : (moved << 16);
      const float bias = __uint_as_float(sel);
      const float v = acc[r] + bias;
      P[sl * 32 + l31][h] = (__bf16)v;
    }
  }
  __syncthreads();

  // -------- writer MFMA: [1024 x 16] @ [16 x 64] --------
  // B-frags: even/odd channel interleave -> lane owns c = 2*l31, 2*l31+1
  bf16x8 wfrag0, wfrag1;
#pragma unroll
  for (int e = 0; e < 8; ++e) {
    const int hh = half * 8 + e;
    wfrag0[e] = (__bf16)((hh < NH) ? Wout[hh * 64 + 2 * l31] : 0.f);
    wfrag1[e] = (__bf16)((hh < NH) ? Wout[hh * 64 + 2 * l31 + 1] : 0.f);
  }
  const float bo0 = bout[2 * l31];
  const float bo1 = bout[2 * l31 + 1];

  float* obase = out + ((((size_t)b << 10) + s0) << 10) * 64 + (size_t)t0 * 64;
#pragma unroll 1
  for (int rt = w; rt < 32; rt += 4) {
    bf16x8 af = *(const bf16x8*)&P[rt * 32 + l31][half * 8];
    f32x16 o0, o1;
#pragma unroll
    for (int e = 0; e < 16; ++e) { o0[e] = 0.f; o1[e] = 0.f; }
    o0 = __builtin_amdgcn_mfma_f32_32x32x16_bf16(af, wfrag0, o0, 0, 0, 0);
    o1 = __builtin_amdgcn_mfma_f32_32x32x16_bf16(af, wfrag1, o1, 0, 0, 0);
    float* orow = obase + ((size_t)rt << 16) + 2 * l31;  // [sl=rt][...]
#pragma unroll
    for (int r = 0; r < 16; ++r) {
      const int tl = (r & 3) + 8 * (r >> 2) + 4 * half;
      f32x2 v;
      v.x = o0[r] + bo0;
      v.y = o1[r] + bo1;
      __builtin_nontemporal_store(v, (f32x2*)(orow + ((size_t)tl << 6)));
    }
  }
}

// ---------------------------------------------------------------------------
extern "C" void kernel_launch(void* const* d_in, const int* in_sizes, int n_in,
                              void* d_out, int out_size, void* d_ws,
                              size_t ws_size, hipStream_t stream) {
  const float* p1 = (const float*)d_in[1];
  const float* Wqk = (const float*)d_in[3];
  const float* bqk = (const float*)d_in[4];
  const float* rel = (const float*)d_in[5];
  const float* Wout = (const float*)d_in[6];
  const float* bout = (const float*)d_in[7];
  float* out = (float*)d_out;

  // ws layout: qf bf16 [2*12*4*2*1024*8] (3.15 MB) | kf same (3.15 MB)
  __bf16* qf = (__bf16*)d_ws;
  __bf16* kf = qf + 1572864;

  hipLaunchKernelGGL(qk_gemm, dim3(32, 24), dim3(256), 0, stream, p1, Wqk, bqk,
                     qf, kf);
  hipLaunchKernelGGL(main_kernel, dim3(SEQ / 32, SEQ / 32, BATCH), dim3(256),
                     0, stream, qf, kf, rel, Wout, bout, out);
}

// Round 14
// 133.366 us; speedup vs baseline: 1.0036x; 1.0036x over previous
//
#include <hip/hip_runtime.h>
#include <math.h>

// Problem constants (B=2, S=1024, H=12, HS=64, ALL=768, P=128)
#define SEQ   1024
#define BATCH 2
#define NH    12
#define ALLD  768
// 1/scaling = 1/64^0.25
#define INVS  0.35355339059327373f

typedef __attribute__((ext_vector_type(8)))  __bf16 bf16x8;
typedef __attribute__((ext_vector_type(16))) float  f32x16;
typedef __attribute__((ext_vector_type(2)))  float  f32x2;

// ---------------------------------------------------------------------------
// K1: u = p1 @ W_qk + b_qk, scaled by INVS; emit q/k in MFMA frag layout.
//   qf/kf [b][h][ks4][half][row][8]   (bf16)
// (unchanged since R7 — part of every anchor measurement)
// ---------------------------------------------------------------------------
__global__ __launch_bounds__(256) void qk_gemm(
    const float* __restrict__ p1, const float* __restrict__ Wqk,
    const float* __restrict__ bqk, __bf16* __restrict__ qf,
    __bf16* __restrict__ kf) {
  const int tid = threadIdx.x;
  const int l = tid & 63, w = tid >> 6;
  const int l31 = l & 31, half = l >> 5;
  const int m0 = blockIdx.x * 64;
  const int mw = (w >> 1) * 32;
  const int nw = blockIdx.y * 64 + (w & 1) * 32;

  __shared__ __bf16 Af[8][66][8];  // 8448 B, padded rows -> conflict-free

  f32x16 acc;
#pragma unroll
  for (int e = 0; e < 16; ++e) acc[e] = 0.f;

  const int arow = tid >> 2;       // 0..63
  const int aq = tid & 3;          // k-quarter (16 floats)

  for (int kk = 0; kk < 768; kk += 64) {
    __syncthreads();  // WAR on Af
    {
      const float* ap = p1 + (size_t)(m0 + arow) * 768 + kk + aq * 16;
      float4 a0 = ((const float4*)ap)[0];
      float4 a1 = ((const float4*)ap)[1];
      float4 a2 = ((const float4*)ap)[2];
      float4 a3 = ((const float4*)ap)[3];
      bf16x8 f0, f1;
      f0[0] = (__bf16)a0.x; f0[1] = (__bf16)a0.y;
      f0[2] = (__bf16)a0.z; f0[3] = (__bf16)a0.w;
      f0[4] = (__bf16)a1.x; f0[5] = (__bf16)a1.y;
      f0[6] = (__bf16)a1.z; f0[7] = (__bf16)a1.w;
      f1[0] = (__bf16)a2.x; f1[1] = (__bf16)a2.y;
      f1[2] = (__bf16)a2.z; f1[3] = (__bf16)a2.w;
      f1[4] = (__bf16)a3.x; f1[5] = (__bf16)a3.y;
      f1[6] = (__bf16)a3.z; f1[7] = (__bf16)a3.w;
      *(bf16x8*)&Af[aq * 2 + 0][arow][0] = f0;
      *(bf16x8*)&Af[aq * 2 + 1][arow][0] = f1;
    }
    __syncthreads();
#pragma unroll
    for (int ksl = 0; ksl < 4; ++ksl) {
      const float* bsrc =
          Wqk + (size_t)(kk + ksl * 16 + half * 8) * 1536 + nw + l31;
      bf16x8 bf;
#pragma unroll
      for (int e = 0; e < 8; ++e) bf[e] = (__bf16)bsrc[(size_t)e * 1536];
      bf16x8 af = *(const bf16x8*)&Af[ksl * 2 + half][mw + l31][0];
      acc = __builtin_amdgcn_mfma_f32_32x32x16_bf16(af, bf, acc, 0, 0, 0);
    }
  }

  const int n = nw + l31;
  const float bias = bqk[n];
  const bool is_q = (n < ALLD);
  const int nn = is_q ? n : n - ALLD;
  const int h = nn >> 6, dd = nn & 63;
  const int ks4 = dd >> 4, hf = (dd >> 3) & 1, e = dd & 7;
  __bf16* fdst = is_q ? qf : kf;
#pragma unroll
  for (int r = 0; r < 16; ++r) {
    const int m = m0 + mw + (r & 3) + 8 * (r >> 2) + 4 * half;
    const int bb = m >> 10, ss = m & 1023;
    const float v = (acc[r] + bias) * INVS;
    fdst[((((size_t)(bb * NH + h) * 4 + ks4) * 2 + hf) * SEQ + ss) * 8 + e] =
        (__bf16)v;
  }
}

// ---------------------------------------------------------------------------
// K2: fused scores + in-tile rel bias + writer + nt-store.
// EXACT R12 version (133.4 us, absmax 5.86e-3) — the measured optimum.
// Journal of rejected "improvements" against this anchor:
//   R8  single-shfl epilogue + INVS fold    -> 151.2 (regalloc regression)
//   R11 two-tile blocks (halved overhead)   -> 148.4 (occupancy loss)
//   R13 packed cvt_pk epilogue (48 shfl)    -> 133.8 neutral, absmax 1.59e-2
// Structure is VGPR-occupancy-bound at 4 blocks/CU (48-VGPR acc set caps
// waves); remaining gap over the ~106 us write-floor model is phase
// serialization that more waves would hide — unreachable at this VGPR count.
// ---------------------------------------------------------------------------
__global__ __launch_bounds__(256, 4) void main_kernel(
    const __bf16* __restrict__ qf, const __bf16* __restrict__ kf,
    const float* __restrict__ rel, const float* __restrict__ Wout,
    const float* __restrict__ bout, float* __restrict__ out) {
  const int tid = threadIdx.x;
  const int l = tid & 63, w = tid >> 6;
  const int l31 = l & 31, half = l >> 5;

  // bijective XCD swizzle (nwg = 2048, divisible by 8)
  const int raw = blockIdx.x + (blockIdx.y << 5) + (blockIdx.z << 10);
  const int swz = (raw & 7) * 256 + (raw >> 3);
  const int t0 = (swz & 31) * 32;
  const int s0 = ((swz >> 5) & 31) * 32;
  const int b = swz >> 10;
  const int D = t0 - s0;

  __shared__ __bf16 P[1024][20];  // 40 KB, padded rows -> conflict-free

  // ---- bias B-frags straight from global rel (66 KB, L2-resident):
  //      panel col c = cb*32 + l31  <->  d = D-32+c  (2 ids per lane)
  bf16x8 relfrag[4][2];
#pragma unroll
  for (int cb = 0; cb < 2; ++cb) {
    const int c = cb * 32 + l31;
    const int d = D - 32 + c;
    const int id = (d >= 0) ? (d < 127 ? d : 127) : (d > -127 ? d + 256 : 129);
    const float* rrow = rel + (size_t)id * 64 + half * 8;
#pragma unroll
    for (int ks = 0; ks < 4; ++ks) {
      float4 r0 = *(const float4*)(rrow + ks * 16);
      float4 r1 = *(const float4*)(rrow + ks * 16 + 4);
      bf16x8 f;
      f[0] = (__bf16)r0.x; f[1] = (__bf16)r0.y;
      f[2] = (__bf16)r0.z; f[3] = (__bf16)r0.w;
      f[4] = (__bf16)r1.x; f[5] = (__bf16)r1.y;
      f[6] = (__bf16)r1.z; f[7] = (__bf16)r1.w;
      relfrag[ks][cb] = f;
    }
  }

  // zero the pad heads 12..15
  {
    ushort4 z = {0, 0, 0, 0};
#pragma unroll
    for (int i = 0; i < 4; ++i) *(ushort4*)&P[tid * 4 + i][12] = z;
  }

  const bf16x8* qfp = (const bf16x8*)qf;
  const bf16x8* kfp = (const bf16x8*)kf;

  // -------- QK + bias phase: 3 heads per wave --------
#pragma unroll
  for (int hh = 0; hh < 3; ++hh) {
    const int h = w * 3 + hh;
    f32x16 acc, bacc0, bacc1;
#pragma unroll
    for (int e = 0; e < 16; ++e) { acc[e] = 0.f; bacc0[e] = 0.f; bacc1[e] = 0.f; }
#pragma unroll
    for (int ks = 0; ks < 4; ++ks) {
      const size_t pbase = (((size_t)(b * NH + h) * 4 + ks) * 2 + half) * SEQ;
      bf16x8 af = qfp[pbase + s0 + l31];
      bf16x8 bvk = kfp[pbase + t0 + l31];
      acc = __builtin_amdgcn_mfma_f32_32x32x16_bf16(af, bvk, acc, 0, 0, 0);
      bacc0 = __builtin_amdgcn_mfma_f32_32x32x16_bf16(af, relfrag[ks][0],
                                                      bacc0, 0, 0, 0);
      bacc1 = __builtin_amdgcn_mfma_f32_32x32x16_bf16(af, relfrag[ks][1],
                                                      bacc1, 0, 0, 0);
    }
    // diagonal extract (R7 form): 2x shfl + select
#pragma unroll
    for (int r = 0; r < 16; ++r) {
      const int sl = (r & 3) + 8 * (r >> 2) + 4 * half;
      const int src = (l31 - sl) & 31;
      const float v0 = __shfl(bacc0[r], src, 32);
      const float v1 = __shfl(bacc1[r], src, 32);
      const float bias = (l31 >= sl) ? v1 : v0;
      const float v = acc[r] + bias * INVS;
      P[sl * 32 + l31][h] = (__bf16)v;
    }
  }
  __syncthreads();

  // -------- writer MFMA: [1024 x 16] @ [16 x 64] --------
  // B-frags: even/odd channel interleave -> lane owns c = 2*l31, 2*l31+1
  bf16x8 wfrag0, wfrag1;
#pragma unroll
  for (int e = 0; e < 8; ++e) {
    const int hh = half * 8 + e;
    wfrag0[e] = (__bf16)((hh < NH) ? Wout[hh * 64 + 2 * l31] : 0.f);
    wfrag1[e] = (__bf16)((hh < NH) ? Wout[hh * 64 + 2 * l31 + 1] : 0.f);
  }
  const float bo0 = bout[2 * l31];
  const float bo1 = bout[2 * l31 + 1];

  float* obase = out + ((((size_t)b << 10) + s0) << 10) * 64 + (size_t)t0 * 64;
#pragma unroll 1
  for (int rt = w; rt < 32; rt += 4) {
    bf16x8 af = *(const bf16x8*)&P[rt * 32 + l31][half * 8];
    f32x16 o0, o1;
#pragma unroll
    for (int e = 0; e < 16; ++e) { o0[e] = 0.f; o1[e] = 0.f; }
    o0 = __builtin_amdgcn_mfma_f32_32x32x16_bf16(af, wfrag0, o0, 0, 0, 0);
    o1 = __builtin_amdgcn_mfma_f32_32x32x16_bf16(af, wfrag1, o1, 0, 0, 0);
    float* orow = obase + ((size_t)rt << 16) + 2 * l31;  // [sl=rt][...]
#pragma unroll
    for (int r = 0; r < 16; ++r) {
      const int tl = (r & 3) + 8 * (r >> 2) + 4 * half;
      f32x2 v;
      v.x = o0[r] + bo0;
      v.y = o1[r] + bo1;
      __builtin_nontemporal_store(v, (f32x2*)(orow + ((size_t)tl << 6)));
    }
  }
}

// ---------------------------------------------------------------------------
extern "C" void kernel_launch(void* const* d_in, const int* in_sizes, int n_in,
                              void* d_out, int out_size, void* d_ws,
                              size_t ws_size, hipStream_t stream) {
  const float* p1 = (const float*)d_in[1];
  const float* Wqk = (const float*)d_in[3];
  const float* bqk = (const float*)d_in[4];
  const float* rel = (const float*)d_in[5];
  const float* Wout = (const float*)d_in[6];
  const float* bout = (const float*)d_in[7];
  float* out = (float*)d_out;

  // ws layout: qf bf16 [2*12*4*2*1024*8] (3.15 MB) | kf same (3.15 MB)
  __bf16* qf = (__bf16*)d_ws;
  __bf16* kf = qf + 1572864;

  hipLaunchKernelGGL(qk_gemm, dim3(32, 24), dim3(256), 0, stream, p1, Wqk, bqk,
                     qf, kf);
  hipLaunchKernelGGL(main_kernel, dim3(SEQ / 32, SEQ / 32, BATCH), dim3(256),
                     0, stream, qf, kf, rel, Wout, bout, out);
}